// Round 1
// baseline (5025.474 us; speedup 1.0000x reference)
//
#include <hip/hip_runtime.h>
#include <hip/hip_bf16.h>
#include <stdint.h>
#include <math.h>

// Problem constants (fixed by the reference)
#define SEQ    2048
#define EMB    1024
#define HID    1024
#define G4     4096      // 4*HID
#define NEMO   16
#define NLAB   7

// LSTM persistent-kernel partition: 128 blocks x 256 threads.
// Block b owns 8 hidden units -> 32 gate rows (4 gates x 8 units).
// Thread t: wave wv = t>>6 handles rows {wv, wv+4, ..., wv+28} over h-columns
// [lane*16, lane*16+16). W fragment = 8x16 = 128 VGPRs.
#define NB 128

__device__ __forceinline__ float sigf(float x) { return 1.0f / (1.0f + expf(-x)); }

// ---------------- k_init: emoji average + htag reset ----------------
__global__ void k_init(const int* __restrict__ emoji_ids,
                       const float* __restrict__ emoji_emb,
                       float* __restrict__ eave,
                       unsigned long long* __restrict__ htag)
{
    int t = threadIdx.x;
    int ids[NEMO];
#pragma unroll
    for (int n = 0; n < NEMO; ++n) ids[n] = emoji_ids[n];
    for (int e = t; e < EMB; e += 256) {
        float s = 0.f;
#pragma unroll
        for (int n = 0; n < NEMO; ++n) s += emoji_emb[(size_t)ids[n] * EMB + e];
        eave[e] = s * (1.0f / 16.0f);
    }
    // htag[2][HID]: tag=0, value=0.0f  (h_{-1} = zeros, parity-1 buffer)
    for (int i = t; i < 2 * HID; i += 256) htag[i] = 0ull;
}

// ---------------- k_cvec: cvec = comb_W[:,1024:] @ eave + comb_b ----------------
__global__ void k_cvec(const float* __restrict__ combW,
                       const float* __restrict__ combB,
                       const float* __restrict__ eave,
                       float* __restrict__ cvec)
{
    // 64 blocks x 256 threads = 256 waves; 4 rows per wave
    int gw   = (blockIdx.x * 256 + threadIdx.x) >> 6;
    int lane = threadIdx.x & 63;
#pragma unroll
    for (int rr = 0; rr < 4; ++rr) {
        int r = gw * 4 + rr;
        const float* wrow = combW + (size_t)r * 2048 + 1024;
        float s = 0.f;
        for (int k = lane; k < EMB; k += 64) s = fmaf(wrow[k], eave[k], s);
#pragma unroll
        for (int off = 1; off < 64; off <<= 1) s += __shfl_xor(s, off);
        if (lane == 0) cvec[r] = s + combB[r];
    }
}

// ---------------- k_gemm: O[m][n] = sum_k Arow(m)[k]*B[n*bstride+k] + bias (+relu) ----
// BM=BN=128, BK=16, 256 threads, 8x8 microtile. K fixed at 1024, dims divide evenly.
__global__ __launch_bounds__(256) void k_gemm(
    const float* __restrict__ Asrc,
    const int*   __restrict__ ids,       // if non-null: A row m = emb[ids[m]]
    const float* __restrict__ emb,
    const float* __restrict__ B, int bstride,
    const float* __restrict__ bias1,
    const float* __restrict__ bias2,     // optional second bias
    float* __restrict__ O, int N, int relu)
{
    __shared__ float As[16][128];
    __shared__ float Bs[16][128];
    const int tid  = threadIdx.x;
    const int row0 = blockIdx.y * 128;
    const int col0 = blockIdx.x * 128;
    const int lr = tid >> 2;     // 0..63: staging row
    const int kq = tid & 3;      // 0..3 : k quad
    const float *ar0, *ar1;
    if (ids) {
        ar0 = emb + (size_t)ids[row0 + lr]      * 1024;
        ar1 = emb + (size_t)ids[row0 + lr + 64] * 1024;
    } else {
        ar0 = Asrc + (size_t)(row0 + lr)      * 1024;
        ar1 = Asrc + (size_t)(row0 + lr + 64) * 1024;
    }
    const float* br0 = B + (size_t)(col0 + lr)      * bstride;
    const float* br1 = B + (size_t)(col0 + lr + 64) * bstride;
    const int tx = tid & 15, ty = tid >> 4;

    float acc[8][8];
#pragma unroll
    for (int i = 0; i < 8; ++i)
#pragma unroll
        for (int j = 0; j < 8; ++j) acc[i][j] = 0.f;

    for (int k0 = 0; k0 < 1024; k0 += 16) {
        float4 a0 = *(const float4*)(ar0 + k0 + kq * 4);
        float4 a1 = *(const float4*)(ar1 + k0 + kq * 4);
        float4 b0 = *(const float4*)(br0 + k0 + kq * 4);
        float4 b1 = *(const float4*)(br1 + k0 + kq * 4);
        __syncthreads();
        {
            const float* pa0 = &a0.x; const float* pa1 = &a1.x;
            const float* pb0 = &b0.x; const float* pb1 = &b1.x;
#pragma unroll
            for (int e = 0; e < 4; ++e) {
                As[kq * 4 + e][lr]      = pa0[e];
                As[kq * 4 + e][lr + 64] = pa1[e];
                Bs[kq * 4 + e][lr]      = pb0[e];
                Bs[kq * 4 + e][lr + 64] = pb1[e];
            }
        }
        __syncthreads();
#pragma unroll
        for (int kk = 0; kk < 16; ++kk) {
            float af[8], bf[8];
            *(float4*)(af)     = *(const float4*)&As[kk][ty * 8];
            *(float4*)(af + 4) = *(const float4*)&As[kk][ty * 8 + 4];
            *(float4*)(bf)     = *(const float4*)&Bs[kk][tx * 8];
            *(float4*)(bf + 4) = *(const float4*)&Bs[kk][tx * 8 + 4];
#pragma unroll
            for (int i = 0; i < 8; ++i)
#pragma unroll
                for (int j = 0; j < 8; ++j)
                    acc[i][j] = fmaf(af[i], bf[j], acc[i][j]);
        }
    }
    // epilogue
    float bv[8];
    *(float4*)(bv)     = *(const float4*)&bias1[col0 + tx * 8];
    *(float4*)(bv + 4) = *(const float4*)&bias1[col0 + tx * 8 + 4];
    if (bias2) {
        float b2[8];
        *(float4*)(b2)     = *(const float4*)&bias2[col0 + tx * 8];
        *(float4*)(b2 + 4) = *(const float4*)&bias2[col0 + tx * 8 + 4];
#pragma unroll
        for (int j = 0; j < 8; ++j) bv[j] += b2[j];
    }
#pragma unroll
    for (int i = 0; i < 8; ++i) {
        int m = row0 + ty * 8 + i;
        float o[8];
#pragma unroll
        for (int j = 0; j < 8; ++j) {
            float v = acc[i][j] + bv[j];
            o[j] = relu ? fmaxf(v, 0.f) : v;
        }
        *(float4*)&O[(size_t)m * N + col0 + tx * 8]     = *(float4*)(o);
        *(float4*)&O[(size_t)m * N + col0 + tx * 8 + 4] = *(float4*)(o + 4);
    }
}

// ---------------- k_lstm: persistent sequential scan ----------------
// htag[2][HID] slots: (tag<<32)|float_bits, agent-scope atomics (coherent across XCDs).
// Step s: reads parity (s+1)&1 expecting tag s; writes parity s&1 with tag s+1.
__global__ __launch_bounds__(256, 1) void k_lstm(
    const float* __restrict__ Whh,     // [4096][1024]
    const float* __restrict__ Gin,     // [2048][4096] precomputed input-gate terms
    unsigned long long* __restrict__ htag)
{
    const int b    = blockIdx.x;    // 0..127, owns units [8b, 8b+8)
    const int t    = threadIdx.x;   // 0..255
    const int lane = t & 63;
    const int wv   = t >> 6;        // wave id 0..3

    // W_hh fragment: 8 rows (wv+4i), cols [lane*16, lane*16+16)
    float w[8][16];
#pragma unroll
    for (int i = 0; i < 8; ++i) {
        int r = wv + 4 * i;
        int grow = ((r >> 3) << 10) + (b << 3) + (r & 7);
        const float4* p = (const float4*)(Whh + (size_t)grow * HID + lane * 16);
#pragma unroll
        for (int q = 0; q < 4; ++q) {
            float4 a = p[q];
            w[i][4 * q + 0] = a.x; w[i][4 * q + 1] = a.y;
            w[i][4 * q + 2] = a.z; w[i][4 * q + 3] = a.w;
        }
    }

    __shared__ float4 hl4[256];        // h, float4-swizzled: hl4[j4*64+col] = h[col*16+j4*4 ..]
    __shared__ float  red[32 * 72];    // per-row partials, padded stride 72
    __shared__ float  gat[32];         // 32 gate pre-activations
    __shared__ float  cst[8];          // persistent cell state (this block's units)
    if (t < 8) cst[t] = 0.f;

    const int s_j4 = t & 3, s_col = t >> 2;     // staging slot for h values 4t..4t+3
    const int rr = t >> 3, kk = t & 7;          // reduction role
    const int growR = ((rr >> 3) << 10) + (b << 3) + (rr & 7);
    unsigned long long* myslots0 = htag + 4 * t;  // + parity*HID at use

    for (int s = 0; s < SEQ; ++s) {
        // prefetch this step's G_in rows (independent of h) — one per row
        float gval = 0.f;
        if (kk == 0) gval = Gin[(size_t)s * G4 + growR];

        // poll h_{s-1}: 4 tagged slots per thread
        unsigned long long* src = myslots0 + (size_t)(((unsigned)(s + 1)) & 1u) * HID;
        const unsigned expw = (unsigned)s;
        unsigned long long v0, v1, v2, v3;
        for (;;) {
            v0 = __hip_atomic_load(src + 0, __ATOMIC_RELAXED, __HIP_MEMORY_SCOPE_AGENT);
            v1 = __hip_atomic_load(src + 1, __ATOMIC_RELAXED, __HIP_MEMORY_SCOPE_AGENT);
            v2 = __hip_atomic_load(src + 2, __ATOMIC_RELAXED, __HIP_MEMORY_SCOPE_AGENT);
            v3 = __hip_atomic_load(src + 3, __ATOMIC_RELAXED, __HIP_MEMORY_SCOPE_AGENT);
            int ok = ((unsigned)(v0 >> 32) == expw) & ((unsigned)(v1 >> 32) == expw) &
                     ((unsigned)(v2 >> 32) == expw) & ((unsigned)(v3 >> 32) == expw);
            if (__all(ok)) break;
        }
        hl4[s_j4 * 64 + s_col] = make_float4(
            __uint_as_float((unsigned)v0), __uint_as_float((unsigned)v1),
            __uint_as_float((unsigned)v2), __uint_as_float((unsigned)v3));
        __syncthreads();   // S1: h staged

        float hf[16];
#pragma unroll
        for (int q = 0; q < 4; ++q) {
            float4 hv = hl4[q * 64 + lane];
            hf[4 * q + 0] = hv.x; hf[4 * q + 1] = hv.y;
            hf[4 * q + 2] = hv.z; hf[4 * q + 3] = hv.w;
        }
        float p[8];
#pragma unroll
        for (int i = 0; i < 8; ++i) p[i] = 0.f;
#pragma unroll
        for (int j = 0; j < 16; ++j)
#pragma unroll
            for (int i = 0; i < 8; ++i)
                p[i] = fmaf(w[i][j], hf[j], p[i]);
#pragma unroll
        for (int i = 0; i < 8; ++i) red[(wv + 4 * i) * 72 + lane] = p[i];
        __syncthreads();   // S2: partials written

        float rs = 0.f;
#pragma unroll
        for (int j = 0; j < 8; ++j) rs += red[rr * 72 + j * 8 + kk];
        rs += __shfl_xor(rs, 1);
        rs += __shfl_xor(rs, 2);
        rs += __shfl_xor(rs, 4);
        if (kk == 0) gat[rr] = rs + gval;
        __syncthreads();   // S3: gates assembled

        if (t < 8) {
            float gi = gat[t], gf = gat[8 + t], gg = gat[16 + t], go = gat[24 + t];
            float c = sigf(gf) * cst[t] + sigf(gi) * tanhf(gg);
            cst[t] = c;
            float h = sigf(go) * tanhf(c);
            unsigned long long pk =
                ((unsigned long long)(unsigned)(s + 1) << 32) |
                (unsigned long long)__float_as_uint(h);
            __hip_atomic_store(htag + (size_t)(((unsigned)s) & 1u) * HID + b * 8 + t,
                               pk, __ATOMIC_RELAXED, __HIP_MEMORY_SCOPE_AGENT);
        }
        // No trailing barrier needed: next step's S1/S2 protect all shared buffers.
    }
}

// ---------------- k_out: out = out_W @ h_final + out_b ----------------
__global__ void k_out(const float* __restrict__ outW,
                      const float* __restrict__ outb,
                      const unsigned long long* __restrict__ htag,
                      float* __restrict__ out)
{
    int wv = threadIdx.x >> 6, lane = threadIdx.x & 63;   // 7 waves
    if (wv < NLAB) {
        float s = 0.f;
        for (int k = lane; k < HID; k += 64) {
            float h = __uint_as_float((unsigned)(htag[HID + k] & 0xffffffffULL));
            s = fmaf(outW[wv * HID + k], h, s);
        }
#pragma unroll
        for (int off = 1; off < 64; off <<= 1) s += __shfl_xor(s, off);
        if (lane == 0) out[wv] = s + outb[wv];
    }
}

extern "C" void kernel_launch(void* const* d_in, const int* in_sizes, int n_in,
                              void* d_out, int out_size, void* d_ws, size_t ws_size,
                              hipStream_t stream)
{
    const int*   sent_ids = (const int*)  d_in[0];
    const int*   emo_ids  = (const int*)  d_in[1];
    const float* word_emb = (const float*)d_in[2];
    const float* emo_emb  = (const float*)d_in[3];
    // d_in[4] attn_W, d_in[5] attn_b: unused — softmax over a single logit == 1.0
    const float* comb_W   = (const float*)d_in[6];
    const float* comb_b   = (const float*)d_in[7];
    const float* W_ih     = (const float*)d_in[8];
    const float* W_hh     = (const float*)d_in[9];
    const float* b_ih     = (const float*)d_in[10];
    const float* b_hh     = (const float*)d_in[11];
    const float* out_W    = (const float*)d_in[12];
    const float* out_b    = (const float*)d_in[13];
    float* out = (float*)d_out;

    float* ws   = (float*)d_ws;
    float* eave = ws;                                   // 1024
    float* cvec = ws + 1024;                            // 1024 (pad to 4096)
    float* C    = ws + 4096;                            // 2048*1024
    float* G    = ws + 4096 + (size_t)SEQ * EMB;        // 2048*4096
    unsigned long long* htag =
        (unsigned long long*)(ws + 4096 + (size_t)SEQ * EMB + (size_t)SEQ * G4); // 2*1024 u64

    k_init<<<1, 256, 0, stream>>>(emo_ids, emo_emb, eave, htag);
    k_cvec<<<64, 256, 0, stream>>>(comb_W, comb_b, eave, cvec);
    // C = relu( gather(word_emb, sent_ids) @ W_x^T + cvec ),  W_x = comb_W[:, :1024]
    dim3 g1(EMB / 128, SEQ / 128);
    k_gemm<<<g1, 256, 0, stream>>>(nullptr, sent_ids, word_emb,
                                   comb_W, 2048, cvec, nullptr, C, EMB, 1);
    // G = C @ W_ih^T + b_ih + b_hh
    dim3 g2(G4 / 128, SEQ / 128);
    k_gemm<<<g2, 256, 0, stream>>>(C, nullptr, nullptr,
                                   W_ih, 1024, b_ih, b_hh, G, G4, 0);
    k_lstm<<<NB, 256, 0, stream>>>(W_hh, G, htag);
    k_out<<<1, 448, 0, stream>>>(out_W, out_b, htag, out);
}